// Round 10
// baseline (266.765 us; speedup 1.0000x reference)
//
#include <hip/hip_runtime.h>
#include <math.h>

#define TPB 256

constexpr int ISZ = 1024;   // feature dim
constexpr int NB  = 64;     // batch
constexpr int NL  = 20;     // headers per example
constexpr int NM  = 16;     // tokens per header
constexpr int NT  = NB * NL; // 1280 header-units

typedef __attribute__((ext_vector_type(8))) short  bf16x8;
typedef __attribute__((ext_vector_type(4))) float  f32x4;

struct Args {
    const float *ctx, *wemb, *U_w, *U_b, *V_w, *enc_w, *enc_b, *gamma, *beta;
    float *uv, *Upart, *cenc, *out;
    unsigned *flags;
    unsigned short *Vth, *Vtl, *encb, *pooledb;
};

__device__ __forceinline__ unsigned short f2bf(float x) {
    unsigned int u = __builtin_bit_cast(unsigned int, x);
    unsigned int r = (u + 0x7fff + ((u >> 16) & 1)) >> 16;   // RNE
    return (unsigned short)r;
}
__device__ __forceinline__ float bf2f(unsigned short h) {
    unsigned int u = ((unsigned int)h) << 16;
    return __builtin_bit_cast(float, u);
}
__device__ __forceinline__ void split4(float4 v, ushort4& h, ushort4& l) {
    h.x = f2bf(v.x); l.x = f2bf(v.x - bf2f(h.x));
    h.y = f2bf(v.y); l.y = f2bf(v.y - bf2f(h.y));
    h.z = f2bf(v.z); l.z = f2bf(v.z - bf2f(h.z));
    h.w = f2bf(v.w); l.w = f2bf(v.w - bf2f(h.w));
}
__device__ __forceinline__ void gld_lds16(const void* g, void* l) {
    __builtin_amdgcn_global_load_lds(
        (const __attribute__((address_space(1))) unsigned int*)g,
        (__attribute__((address_space(3))) unsigned int*)l, 16, 0, 0);
}
// RMW-based flag peek: executes at the coherent point -> never stale
__device__ __forceinline__ unsigned rmw_peek(unsigned* p) {
    return __hip_atomic_fetch_add(p, 0u, __ATOMIC_ACQUIRE, __HIP_MEMORY_SCOPE_AGENT);
}
__device__ __forceinline__ void sig(unsigned* p) {
    __hip_atomic_fetch_add(p, 1u, __ATOMIC_RELEASE, __HIP_MEMORY_SCOPE_AGENT);
}

// ---------------------------------------------------------------------------
// LDS 64x64 bf16 tiles (8 KB each): Ah=+0, Al=+8K, Bh=+16K, Bl=+24K
// mapping: LDS[row][byte ^ ((row&7)<<4)] (128 B rows) — matches frag reads
// ---------------------------------------------------------------------------
__device__ __forceinline__ void stage_hl(const float* __restrict__ src, int ld,
                                         int kbeg, unsigned char* ldsH,
                                         unsigned char* ldsL, int tid)
{
    #pragma unroll
    for (int r = 0; r < 4; ++r) {
        int idx = r * 256 + tid;
        int row = idx >> 4, cg4 = (idx & 15) << 2;
        float4 v = *(const float4*)&src[(size_t)row * ld + kbeg + cg4];
        ushort4 h, l; split4(v, h, l);
        int boff = row * 128 + ((cg4 << 1) ^ ((row & 7) << 4));
        *(ushort4*)(ldsH + boff) = h;
        *(ushort4*)(ldsL + boff) = l;
    }
}
__device__ __forceinline__ void stage_h(const float* __restrict__ src, int ld,
                                        int kbeg, unsigned char* ldsH, int tid)
{
    #pragma unroll
    for (int r = 0; r < 4; ++r) {
        int idx = r * 256 + tid;
        int row = idx >> 4, cg4 = (idx & 15) << 2;
        float4 v = *(const float4*)&src[(size_t)row * ld + kbeg + cg4];
        ushort4 h = { f2bf(v.x), f2bf(v.y), f2bf(v.z), f2bf(v.w) };
        int boff = row * 128 + ((cg4 << 1) ^ ((row & 7) << 4));
        *(ushort4*)(ldsH + boff) = h;
    }
}
// A-stage for uv: wenc_u[row][k] = U_b[k] + sum_s Upart[s][row][k], hi/lo
__device__ __forceinline__ void stage_A_uv(const float* __restrict__ Upart,
                                           const float* __restrict__ U_b,
                                           int kbeg, unsigned char* ldsH,
                                           unsigned char* ldsL, int tid)
{
    #pragma unroll
    for (int r = 0; r < 4; ++r) {
        int idx = r * 256 + tid;
        int row = idx >> 4, cg4 = (idx & 15) << 2;
        int k = kbeg + cg4;
        float4 v = *(const float4*)&U_b[k];
        #pragma unroll
        for (int s = 0; s < 8; ++s) {
            float4 u = *(const float4*)&Upart[(size_t)(s * 64 + row) * ISZ + k];
            v.x += u.x; v.y += u.y; v.z += u.z; v.w += u.w;
        }
        ushort4 h, l; split4(v, h, l);
        int boff = row * 128 + ((cg4 << 1) ^ ((row & 7) << 4));
        *(ushort4*)(ldsH + boff) = h;
        *(ushort4*)(ldsL + boff) = l;
    }
}

__device__ __forceinline__ void comp_hl(const unsigned char* lds, f32x4 acc[2][2], int tid)
{
    const int wid = tid >> 6, lane = tid & 63;
    const int ln = lane & 15, kb = lane >> 4;
    const int wr = wid >> 1, wc = wid & 1;
    #pragma unroll
    for (int ks = 0; ks < 2; ++ks) {
        const int cb = ks * 64 + kb * 16;
        bf16x8 ah[2], al[2], bh[2], bl[2];
        #pragma unroll
        for (int m = 0; m < 2; ++m) {
            int ra = wr * 32 + m * 16 + ln;
            int off = ra * 128 + (cb ^ ((ra & 7) << 4));
            ah[m] = *(const bf16x8*)(lds + off);
            al[m] = *(const bf16x8*)(lds + 8192 + off);
        }
        #pragma unroll
        for (int n = 0; n < 2; ++n) {
            int rb = wc * 32 + n * 16 + ln;
            int off = rb * 128 + (cb ^ ((rb & 7) << 4));
            bh[n] = *(const bf16x8*)(lds + 16384 + off);
            bl[n] = *(const bf16x8*)(lds + 24576 + off);
        }
        #pragma unroll
        for (int m = 0; m < 2; ++m)
            #pragma unroll
            for (int n = 0; n < 2; ++n) {
                acc[m][n] = __builtin_amdgcn_mfma_f32_16x16x32_bf16(ah[m], bh[n], acc[m][n], 0, 0, 0);
                acc[m][n] = __builtin_amdgcn_mfma_f32_16x16x32_bf16(ah[m], bl[n], acc[m][n], 0, 0, 0);
                acc[m][n] = __builtin_amdgcn_mfma_f32_16x16x32_bf16(al[m], bh[n], acc[m][n], 0, 0, 0);
            }
    }
}
__device__ __forceinline__ void comp_h(const unsigned char* lds, f32x4 acc[2][2], int tid)
{
    const int wid = tid >> 6, lane = tid & 63;
    const int ln = lane & 15, kb = lane >> 4;
    const int wr = wid >> 1, wc = wid & 1;
    #pragma unroll
    for (int ks = 0; ks < 2; ++ks) {
        const int cb = ks * 64 + kb * 16;
        bf16x8 ah[2], bh[2];
        #pragma unroll
        for (int m = 0; m < 2; ++m) {
            int ra = wr * 32 + m * 16 + ln;
            ah[m] = *(const bf16x8*)(lds + ra * 128 + (cb ^ ((ra & 7) << 4)));
        }
        #pragma unroll
        for (int n = 0; n < 2; ++n) {
            int rb = wc * 32 + n * 16 + ln;
            bh[n] = *(const bf16x8*)(lds + 16384 + rb * 128 + (cb ^ ((rb & 7) << 4)));
        }
        #pragma unroll
        for (int m = 0; m < 2; ++m)
            #pragma unroll
            for (int n = 0; n < 2; ++n)
                acc[m][n] = __builtin_amdgcn_mfma_f32_16x16x32_bf16(ah[m], bh[n], acc[m][n], 0, 0, 0);
    }
}

// ===========================================================================
// k_front (656 blocks, LB(256,3) -> 768 co-resident guaranteed):
//  [0,128)   Upart[s] = ctx @ U_w^T (hi/lo)            -> sig f0
//  [128,144) cenc = ctx @ enc_w[:,1024:]^T + enc_b     (full-K, direct)
//  [144,400) V^T 64x64 -> Vth/Vtl                      -> sig f1
//  [400,528) encb conversion (8 rows/block)
//  [528,656) uv: RMW-poll f0==128 && f1==256, then uv += wenc_u @ V (atomic)
// ===========================================================================
__global__ __launch_bounds__(TPB, 3)
void k_front(Args A)
{
    __shared__ __align__(16) unsigned char smem[32768];
    const int bid = blockIdx.x, tid = threadIdx.x;
    const int wid = tid >> 6, lane = tid & 63;
    const int wr = wid >> 1, wc = wid & 1;
    const int cl = lane & 15, rg = lane >> 4;

    if (bid < 128) {
        const int s = bid >> 4, n0 = (bid & 15) * 64;
        const int kbeg = s * 128;
        f32x4 acc[2][2] = {};
        for (int kt = 0; kt < 2; ++kt) {
            const int kk = kbeg + kt * 64;
            stage_hl(A.ctx, ISZ, kk, smem, smem + 8192, tid);
            stage_hl(A.U_w + (size_t)n0 * ISZ, ISZ, kk, smem + 16384, smem + 24576, tid);
            __syncthreads();
            comp_hl(smem, acc, tid);
            __syncthreads();
        }
        #pragma unroll
        for (int m = 0; m < 2; ++m)
            #pragma unroll
            for (int n = 0; n < 2; ++n) {
                int col = n0 + wc * 32 + n * 16 + cl;
                #pragma unroll
                for (int j = 0; j < 4; ++j) {
                    int row = wr * 32 + m * 16 + rg * 4 + j;
                    A.Upart[(size_t)(s * 64 + row) * ISZ + col] = acc[m][n][j];
                }
            }
        __threadfence();
        __syncthreads();
        if (tid == 0) sig(&A.flags[0]);
    } else if (bid < 144) {
        const int n0 = (bid - 128) * 64;
        f32x4 acc[2][2] = {};
        for (int kt = 0; kt < 16; ++kt) {
            const int kk = kt * 64;
            stage_h(A.ctx, ISZ, kk, smem, tid);
            stage_h(A.enc_w + (size_t)n0 * 2048 + 1024, 2048, kk, smem + 16384, tid);
            __syncthreads();
            comp_h(smem, acc, tid);
            __syncthreads();
        }
        #pragma unroll
        for (int m = 0; m < 2; ++m)
            #pragma unroll
            for (int n = 0; n < 2; ++n) {
                int col = n0 + wc * 32 + n * 16 + cl;
                #pragma unroll
                for (int j = 0; j < 4; ++j) {
                    int row = wr * 32 + m * 16 + rg * 4 + j;
                    A.cenc[(size_t)row * ISZ + col] = acc[m][n][j] + A.enc_b[col];
                }
            }
    } else if (bid < 400) {
        float (*t)[65] = (float(*)[65])smem;
        const int id = bid - 144;
        const int r0 = (id >> 4) * 64, c0 = (id & 15) * 64;
        const int tr = tid >> 4, tc = (tid & 15) * 4;
        #pragma unroll
        for (int i = 0; i < 4; ++i) {
            float4 v = *(const float4*)&A.V_w[(size_t)(r0 + tr + 16 * i) * ISZ + c0 + tc];
            t[tr + 16 * i][tc + 0] = v.x; t[tr + 16 * i][tc + 1] = v.y;
            t[tr + 16 * i][tc + 2] = v.z; t[tr + 16 * i][tc + 3] = v.w;
        }
        __syncthreads();
        #pragma unroll
        for (int i = 0; i < 4; ++i) {
            int rr = tr + 16 * i;
            float4 v = { t[tc + 0][rr], t[tc + 1][rr], t[tc + 2][rr], t[tc + 3][rr] };
            ushort4 h, l; split4(v, h, l);
            *(ushort4*)&A.Vth[(size_t)(c0 + rr) * ISZ + r0 + tc] = h;
            *(ushort4*)&A.Vtl[(size_t)(c0 + rr) * ISZ + r0 + tc] = l;
        }
        __threadfence();
        __syncthreads();
        if (tid == 0) sig(&A.flags[1]);
    } else if (bid < 528) {
        const int id = bid - 400;
        const int c = tid << 2;
        #pragma unroll
        for (int r = 0; r < 8; ++r) {
            int row = id * 8 + r;
            float4 v = *(const float4*)&A.enc_w[(size_t)row * 2048 + c];
            ushort4 o = { f2bf(v.x), f2bf(v.y), f2bf(v.z), f2bf(v.w) };
            *(ushort4*)&A.encb[(size_t)row * ISZ + c] = o;
        }
    } else {
        if (tid == 0) {
            while (rmw_peek(&A.flags[0]) < 128u) __builtin_amdgcn_s_sleep(16);
            while (rmw_peek(&A.flags[1]) < 256u) __builtin_amdgcn_s_sleep(16);
        }
        __syncthreads();
        __threadfence();   // acquire: invalidate stale cached lines

        const int id = bid - 528;
        const int s = id >> 4, n0 = (id & 15) * 64;
        const int kbeg = s * 128;
        const int srow = lane >> 3, sbyte = (lane & 7) << 4;
        const int swz = sbyte ^ (srow << 4);
        f32x4 acc[2][2] = {};
        for (int kt = 0; kt < 2; ++kt) {
            const int kk = kbeg + kt * 64;
            const int kbyte = kk * 2;
            #pragma unroll
            for (int i = 0; i < 2; ++i) {
                int r = wid * 8 + i * 32 + srow;
                size_t gb = (size_t)(n0 + r) * 2048 + kbyte + swz;
                gld_lds16((const char*)A.Vth + gb, (void*)(smem + 16384 + wid * 1024 + i * 4096));
                gld_lds16((const char*)A.Vtl + gb, (void*)(smem + 24576 + wid * 1024 + i * 4096));
            }
            stage_A_uv(A.Upart, A.U_b, kk, smem, smem + 8192, tid);
            __syncthreads();
            comp_hl(smem, acc, tid);
            __syncthreads();
        }
        #pragma unroll
        for (int m = 0; m < 2; ++m)
            #pragma unroll
            for (int n = 0; n < 2; ++n) {
                int col = n0 + wc * 32 + n * 16 + cl;
                #pragma unroll
                for (int j = 0; j < 4; ++j) {
                    int row = wr * 32 + m * 16 + rg * 4 + j;
                    atomicAdd(&A.uv[(size_t)row * ISZ + col], acc[m][n][j]);
                }
            }
    }
}

// ===========================================================================
// k_back (1024 blocks, LB(256,4) -> exactly 1024 co-resident):
//   phase A: attn tasks t = bid, bid+1024 (reads uv directly)  -> sig f2
//   phase B: blocks < 320 RMW-poll f2==1024, then 64x64 enc GEMM with
//            2-deep counted-vmcnt pipeline (R8-verified body)
// ===========================================================================
__global__ __launch_bounds__(TPB, 4)
void k_back(Args A)
{
    __shared__ __align__(16) unsigned char smem[32768];
    float (*red)[4] = (float(*)[4])smem;
    float* att = (float*)(smem + 256);
    const int bid = blockIdx.x, tid = threadIdx.x;
    const int wid = tid >> 6, lane = tid & 63;

    // ---------------- phase A: attention ----------------
    for (int t = bid; t < NT; t += 1024) {
        const int b = t / NL;
        const float* w = A.wemb + (size_t)t * NM * ISZ;
        const int j0 = tid << 2;
        float4 u4 = *(const float4*)&A.uv[(size_t)b * ISZ + j0];

        float4 wv[NM];
        float part[NM];
        #pragma unroll
        for (int m = 0; m < NM; ++m) {
            wv[m] = *(const float4*)&w[m * ISZ + j0];
            part[m] = wv[m].x * u4.x + wv[m].y * u4.y + wv[m].z * u4.z + wv[m].w * u4.w;
        }
        #pragma unroll
        for (int m = 0; m < NM; ++m) {
            float v = part[m];
            #pragma unroll
            for (int off = 32; off > 0; off >>= 1) v += __shfl_down(v, off, 64);
            if (lane == 0) red[m][wid] = v;
        }
        __syncthreads();
        if (tid < NM) att[tid] = red[tid][0] + red[tid][1] + red[tid][2] + red[tid][3];
        __syncthreads();

        float mx = att[0];
        #pragma unroll
        for (int m = 1; m < NM; ++m) mx = fmaxf(mx, att[m]);
        float p[NM], sm = 0.0f;
        #pragma unroll
        for (int m = 0; m < NM; ++m) { p[m] = __expf(att[m] - mx); sm += p[m]; }
        float inv = 1.0f / sm;

        float4 acc = {0.0f, 0.0f, 0.0f, 0.0f};
        #pragma unroll
        for (int m = 0; m < NM; ++m) {
            float pm = p[m] * inv;
            acc.x += pm * wv[m].x; acc.y += pm * wv[m].y;
            acc.z += pm * wv[m].z; acc.w += pm * wv[m].w;
        }
        ushort4 o;
        o.x = f2bf(acc.x); o.y = f2bf(acc.y); o.z = f2bf(acc.z); o.w = f2bf(acc.w);
        *(ushort4*)&A.pooledb[(size_t)t * ISZ + j0] = o;
        __syncthreads();
    }
    __threadfence();
    __syncthreads();
    if (tid == 0) sig(&A.flags[2]);

    // ---------------- phase B: encoder GEMM ----------------
    if (bid >= 320) return;
    if (tid == 0) {
        while (rmw_peek(&A.flags[2]) < 1024u) __builtin_amdgcn_s_sleep(16);
    }
    __syncthreads();
    __threadfence();

    const int m0 = (bid >> 4) * 64;
    const int n0 = (bid & 15) * 64;
    const int srow = lane >> 3;
    const int swz  = ((lane & 7) << 4) ^ (srow << 4);
    const char* Ab = (const char*)A.pooledb;
    const char* Bb = (const char*)A.encb;

#define STAGE_ENC(kt, buf) do {                                                  \
        const int kbyte_ = (kt) * 128;                                           \
        _Pragma("unroll")                                                        \
        for (int i_ = 0; i_ < 2; ++i_) {                                         \
            int r_ = wid * 8 + i_ * 32 + srow;                                   \
            gld_lds16(Ab + ((size_t)(m0 + r_) * ISZ) * 2 + kbyte_ + swz,         \
                      (void*)(smem + (buf) * 8192 + wid * 1024 + i_ * 4096));    \
            gld_lds16(Bb + ((size_t)(n0 + r_) * ISZ) * 2 + kbyte_ + swz,         \
                      (void*)(smem + 16384 + (buf) * 8192 + wid * 1024 + i_ * 4096)); \
        } } while (0)

    f32x4 acc[2][2] = {};
    STAGE_ENC(0, 0);
    STAGE_ENC(1, 1);

    const int ln = lane & 15, kb = lane >> 4;
    const int wr = wid >> 1, wc = wid & 1;

    for (int kt = 0; kt < 16; ++kt) {
        const int cur = kt & 1;
        if (kt < 15) asm volatile("s_waitcnt vmcnt(4)" ::: "memory");
        else         asm volatile("s_waitcnt vmcnt(0)" ::: "memory");
        __builtin_amdgcn_sched_barrier(0);
        __builtin_amdgcn_s_barrier();
        __builtin_amdgcn_sched_barrier(0);

        #pragma unroll
        for (int ks = 0; ks < 2; ++ks) {
            const int cb = ks * 64 + kb * 16;
            bf16x8 a[2], b[2];
            #pragma unroll
            for (int m = 0; m < 2; ++m) {
                int ra = wr * 32 + m * 16 + ln;
                a[m] = *(const bf16x8*)(smem + cur * 8192 + ra * 128 + (cb ^ ((ra & 7) << 4)));
            }
            #pragma unroll
            for (int n = 0; n < 2; ++n) {
                int rb = wc * 32 + n * 16 + ln;
                b[n] = *(const bf16x8*)(smem + 16384 + cur * 8192 + rb * 128 + (cb ^ ((rb & 7) << 4)));
            }
            #pragma unroll
            for (int m = 0; m < 2; ++m)
                #pragma unroll
                for (int n = 0; n < 2; ++n)
                    acc[m][n] = __builtin_amdgcn_mfma_f32_16x16x32_bf16(a[m], b[n], acc[m][n], 0, 0, 0);
        }

        asm volatile("s_waitcnt lgkmcnt(0)" ::: "memory");
        __builtin_amdgcn_sched_barrier(0);
        __builtin_amdgcn_s_barrier();
        __builtin_amdgcn_sched_barrier(0);
        if (kt < 14) STAGE_ENC(kt + 2, cur);
    }
#undef STAGE_ENC

    const int cl = lane & 15, rg = lane >> 4;
    #pragma unroll
    for (int m = 0; m < 2; ++m)
        #pragma unroll
        for (int n = 0; n < 2; ++n) {
            int col = n0 + wc * 32 + n * 16 + cl;
            #pragma unroll
            for (int j = 0; j < 4; ++j) {
                int row = m0 + wr * 32 + m * 16 + rg * 4 + j;
                A.out[(size_t)row * ISZ + col] =
                    acc[m][n][j] + A.cenc[(size_t)(row / NL) * ISZ + col];
            }
        }
}

// ===========================================================================
// k_ln (1280): TF-style LayerNorm in-place on out
// ===========================================================================
__global__ __launch_bounds__(TPB)
void k_ln(Args A)
{
    __shared__ float rs[4], rs2[4];
    __shared__ float mu_s, rstd_s;
    const int t = blockIdx.x;
    const int tid = threadIdx.x;
    const int lane = tid & 63, wid = tid >> 6;
    const int c = tid << 2;

    float4 v = *(const float4*)&A.out[(size_t)t * ISZ + c];
    float s  = v.x + v.y + v.z + v.w;
    float s2 = v.x * v.x + v.y * v.y + v.z * v.z + v.w * v.w;
    #pragma unroll
    for (int off = 32; off > 0; off >>= 1) {
        s  += __shfl_down(s, off, 64);
        s2 += __shfl_down(s2, off, 64);
    }
    if (lane == 0) { rs[wid] = s; rs2[wid] = s2; }
    __syncthreads();
    if (tid == 0) {
        float S  = rs[0] + rs[1] + rs[2] + rs[3];
        float S2 = rs2[0] + rs2[1] + rs2[2] + rs2[3];
        float m  = S / ISZ;
        float var = S2 / ISZ - m * m;
        mu_s  = m;
        rstd_s = rsqrtf(var + 1e-12f);
    }
    __syncthreads();
    const float mu = mu_s, rstd = rstd_s;
    float4 g  = *(const float4*)&A.gamma[c];
    float4 be = *(const float4*)&A.beta[c];
    float4 o;
    o.x = g.x * (v.x - mu) * rstd + be.x;
    o.y = g.y * (v.y - mu) * rstd + be.y;
    o.z = g.z * (v.z - mu) * rstd + be.z;
    o.w = g.w * (v.w - mu) * rstd + be.w;
    *(float4*)&A.out[(size_t)t * ISZ + c] = o;
}

// ---------------------------------------------------------------------------
extern "C" void kernel_launch(void* const* d_in, const int* in_sizes, int n_in,
                              void* d_out, int out_size, void* d_ws, size_t ws_size,
                              hipStream_t stream)
{
    Args A;
    A.ctx   = (const float*)d_in[0];
    A.wemb  = (const float*)d_in[1];
    // d_in[2] l_hpu, d_in[3] l_hs: constant (16, 20) -> unused
    A.U_w   = (const float*)d_in[4];
    A.U_b   = (const float*)d_in[5];
    A.V_w   = (const float*)d_in[6];
    // d_in[7] V_b: constant logit offset per header, cancels in softmax
    A.enc_w = (const float*)d_in[8];
    A.enc_b = (const float*)d_in[9];
    A.gamma = (const float*)d_in[10];
    A.beta  = (const float*)d_in[11];
    A.out   = (float*)d_out;

    float* ws = (float*)d_ws;
    A.uv    = ws;                                    // 64*1024 f32   (memset 0)
    A.flags = (unsigned*)(ws + NB * ISZ);            // 64 u32        (memset 0)
    A.Upart = (float*)(A.flags + 64);                // 8*64*1024 f32
    A.cenc  = A.Upart + 8 * NB * ISZ;                // 64*1024 f32
    unsigned short* p = (unsigned short*)(A.cenc + NB * ISZ);
    A.Vth     = p;  p += ISZ * ISZ;                  // V^T hi
    A.Vtl     = p;  p += ISZ * ISZ;                  // V^T lo
    A.encb    = p;  p += ISZ * ISZ;                  // enc_w[:, :1024] bf16
    A.pooledb = p;                                   // 1280*1024 bf16

    hipMemsetAsync(A.uv, 0, (size_t)NB * ISZ * sizeof(float) + 64 * sizeof(unsigned),
                   stream);

    k_front<<<656,  TPB, 0, stream>>>(A);
    k_back <<<1024, TPB, 0, stream>>>(A);
    k_ln   <<<NT,   TPB, 0, stream>>>(A);
}

// Round 11
// 125.334 us; speedup vs baseline: 2.1284x; 2.1284x over previous
//
#include <hip/hip_runtime.h>
#include <math.h>

#define TPB 256

constexpr int ISZ = 1024;   // feature dim
constexpr int NB  = 64;     // batch
constexpr int NL  = 20;     // headers per example
constexpr int NM  = 16;     // tokens per header
constexpr int NT  = NB * NL; // 1280 header-units

typedef __attribute__((ext_vector_type(8))) short  bf16x8;
typedef __attribute__((ext_vector_type(4))) float  f32x4;

struct Args {
    const float *ctx, *wemb, *U_w, *U_b, *V_w, *enc_w, *enc_b, *gamma, *beta;
    float *uv, *Upart, *cenc, *out;
    unsigned short *Vth, *Vtl, *encb, *pooledb;
};

__device__ __forceinline__ unsigned short f2bf(float x) {
    unsigned int u = __builtin_bit_cast(unsigned int, x);
    unsigned int r = (u + 0x7fff + ((u >> 16) & 1)) >> 16;   // RNE
    return (unsigned short)r;
}
__device__ __forceinline__ float bf2f(unsigned short h) {
    unsigned int u = ((unsigned int)h) << 16;
    return __builtin_bit_cast(float, u);
}
__device__ __forceinline__ void split4(float4 v, ushort4& h, ushort4& l) {
    h.x = f2bf(v.x); l.x = f2bf(v.x - bf2f(h.x));
    h.y = f2bf(v.y); l.y = f2bf(v.y - bf2f(h.y));
    h.z = f2bf(v.z); l.z = f2bf(v.z - bf2f(h.z));
    h.w = f2bf(v.w); l.w = f2bf(v.w - bf2f(h.w));
}
__device__ __forceinline__ void gld_lds16(const void* g, void* l) {
    __builtin_amdgcn_global_load_lds(
        (const __attribute__((address_space(1))) unsigned int*)g,
        (__attribute__((address_space(3))) unsigned int*)l, 16, 0, 0);
}

// ---------------------------------------------------------------------------
// LDS 64x64 bf16 tiles (8 KB each): Ah=+0, Al=+8K, Bh=+16K, Bl=+24K
// mapping: LDS[row][byte ^ ((row&7)<<4)] (128 B rows) — matches frag reads
// ---------------------------------------------------------------------------
__device__ __forceinline__ void stage_hl(const float* __restrict__ src, int ld,
                                         int kbeg, unsigned char* ldsH,
                                         unsigned char* ldsL, int tid)
{
    #pragma unroll
    for (int r = 0; r < 4; ++r) {
        int idx = r * 256 + tid;
        int row = idx >> 4, cg4 = (idx & 15) << 2;
        float4 v = *(const float4*)&src[(size_t)row * ld + kbeg + cg4];
        ushort4 h, l; split4(v, h, l);
        int boff = row * 128 + ((cg4 << 1) ^ ((row & 7) << 4));
        *(ushort4*)(ldsH + boff) = h;
        *(ushort4*)(ldsL + boff) = l;
    }
}
__device__ __forceinline__ void stage_h(const float* __restrict__ src, int ld,
                                        int kbeg, unsigned char* ldsH, int tid)
{
    #pragma unroll
    for (int r = 0; r < 4; ++r) {
        int idx = r * 256 + tid;
        int row = idx >> 4, cg4 = (idx & 15) << 2;
        float4 v = *(const float4*)&src[(size_t)row * ld + kbeg + cg4];
        ushort4 h = { f2bf(v.x), f2bf(v.y), f2bf(v.z), f2bf(v.w) };
        int boff = row * 128 + ((cg4 << 1) ^ ((row & 7) << 4));
        *(ushort4*)(ldsH + boff) = h;
    }
}
// A-stage for uv: wenc_u[row][k] = U_b[k] + sum_s Upart[s][row][k], hi/lo
__device__ __forceinline__ void stage_A_uv(const float* __restrict__ Upart,
                                           const float* __restrict__ U_b,
                                           int kbeg, unsigned char* ldsH,
                                           unsigned char* ldsL, int tid)
{
    #pragma unroll
    for (int r = 0; r < 4; ++r) {
        int idx = r * 256 + tid;
        int row = idx >> 4, cg4 = (idx & 15) << 2;
        int k = kbeg + cg4;
        float4 v = *(const float4*)&U_b[k];
        #pragma unroll
        for (int s = 0; s < 8; ++s) {
            float4 u = *(const float4*)&Upart[(size_t)(s * 64 + row) * ISZ + k];
            v.x += u.x; v.y += u.y; v.z += u.z; v.w += u.w;
        }
        ushort4 h, l; split4(v, h, l);
        int boff = row * 128 + ((cg4 << 1) ^ ((row & 7) << 4));
        *(ushort4*)(ldsH + boff) = h;
        *(ushort4*)(ldsL + boff) = l;
    }
}

__device__ __forceinline__ void comp_hl(const unsigned char* lds, f32x4 acc[2][2], int tid)
{
    const int wid = tid >> 6, lane = tid & 63;
    const int ln = lane & 15, kb = lane >> 4;
    const int wr = wid >> 1, wc = wid & 1;
    #pragma unroll
    for (int ks = 0; ks < 2; ++ks) {
        const int cb = ks * 64 + kb * 16;
        bf16x8 ah[2], al[2], bh[2], bl[2];
        #pragma unroll
        for (int m = 0; m < 2; ++m) {
            int ra = wr * 32 + m * 16 + ln;
            int off = ra * 128 + (cb ^ ((ra & 7) << 4));
            ah[m] = *(const bf16x8*)(lds + off);
            al[m] = *(const bf16x8*)(lds + 8192 + off);
        }
        #pragma unroll
        for (int n = 0; n < 2; ++n) {
            int rb = wc * 32 + n * 16 + ln;
            int off = rb * 128 + (cb ^ ((rb & 7) << 4));
            bh[n] = *(const bf16x8*)(lds + 16384 + off);
            bl[n] = *(const bf16x8*)(lds + 24576 + off);
        }
        #pragma unroll
        for (int m = 0; m < 2; ++m)
            #pragma unroll
            for (int n = 0; n < 2; ++n) {
                acc[m][n] = __builtin_amdgcn_mfma_f32_16x16x32_bf16(ah[m], bh[n], acc[m][n], 0, 0, 0);
                acc[m][n] = __builtin_amdgcn_mfma_f32_16x16x32_bf16(ah[m], bl[n], acc[m][n], 0, 0, 0);
                acc[m][n] = __builtin_amdgcn_mfma_f32_16x16x32_bf16(al[m], bh[n], acc[m][n], 0, 0, 0);
            }
    }
}
__device__ __forceinline__ void comp_h(const unsigned char* lds, f32x4 acc[2][2], int tid)
{
    const int wid = tid >> 6, lane = tid & 63;
    const int ln = lane & 15, kb = lane >> 4;
    const int wr = wid >> 1, wc = wid & 1;
    #pragma unroll
    for (int ks = 0; ks < 2; ++ks) {
        const int cb = ks * 64 + kb * 16;
        bf16x8 ah[2], bh[2];
        #pragma unroll
        for (int m = 0; m < 2; ++m) {
            int ra = wr * 32 + m * 16 + ln;
            ah[m] = *(const bf16x8*)(lds + ra * 128 + (cb ^ ((ra & 7) << 4)));
        }
        #pragma unroll
        for (int n = 0; n < 2; ++n) {
            int rb = wc * 32 + n * 16 + ln;
            bh[n] = *(const bf16x8*)(lds + 16384 + rb * 128 + (cb ^ ((rb & 7) << 4)));
        }
        #pragma unroll
        for (int m = 0; m < 2; ++m)
            #pragma unroll
            for (int n = 0; n < 2; ++n)
                acc[m][n] = __builtin_amdgcn_mfma_f32_16x16x32_bf16(ah[m], bh[n], acc[m][n], 0, 0, 0);
    }
}

// ===========================================================================
// k_prep (528 blocks, fully independent):
//  [0,128)   Upart[s] = ctx @ U_w^T (hi/lo, k-chunk s)
//  [128,144) cenc = ctx @ enc_w[:,1024:]^T + enc_b  (full-K direct, R10-verified)
//  [144,400) V^T 64x64 -> Vth/Vtl (hi/lo)
//  [400,528) encb: enc_w[:, :1024] -> bf16 (8 rows/block)
// ===========================================================================
__global__ __launch_bounds__(TPB)
void k_prep(Args A)
{
    __shared__ __align__(16) unsigned char smem[32768];
    const int bid = blockIdx.x, tid = threadIdx.x;
    const int wid = tid >> 6, lane = tid & 63;
    const int wr = wid >> 1, wc = wid & 1;
    const int cl = lane & 15, rg = lane >> 4;

    if (bid < 128) {
        const int s = bid >> 4, n0 = (bid & 15) * 64;
        const int kbeg = s * 128;
        f32x4 acc[2][2] = {};
        for (int kt = 0; kt < 2; ++kt) {
            const int kk = kbeg + kt * 64;
            stage_hl(A.ctx, ISZ, kk, smem, smem + 8192, tid);
            stage_hl(A.U_w + (size_t)n0 * ISZ, ISZ, kk, smem + 16384, smem + 24576, tid);
            __syncthreads();
            comp_hl(smem, acc, tid);
            __syncthreads();
        }
        #pragma unroll
        for (int m = 0; m < 2; ++m)
            #pragma unroll
            for (int n = 0; n < 2; ++n) {
                int col = n0 + wc * 32 + n * 16 + cl;
                #pragma unroll
                for (int j = 0; j < 4; ++j) {
                    int row = wr * 32 + m * 16 + rg * 4 + j;
                    A.Upart[(size_t)(s * 64 + row) * ISZ + col] = acc[m][n][j];
                }
            }
    } else if (bid < 144) {
        const int n0 = (bid - 128) * 64;
        f32x4 acc[2][2] = {};
        for (int kt = 0; kt < 16; ++kt) {
            const int kk = kt * 64;
            stage_h(A.ctx, ISZ, kk, smem, tid);
            stage_h(A.enc_w + (size_t)n0 * 2048 + 1024, 2048, kk, smem + 16384, tid);
            __syncthreads();
            comp_h(smem, acc, tid);
            __syncthreads();
        }
        #pragma unroll
        for (int m = 0; m < 2; ++m)
            #pragma unroll
            for (int n = 0; n < 2; ++n) {
                int col = n0 + wc * 32 + n * 16 + cl;
                #pragma unroll
                for (int j = 0; j < 4; ++j) {
                    int row = wr * 32 + m * 16 + rg * 4 + j;
                    A.cenc[(size_t)row * ISZ + col] = acc[m][n][j] + A.enc_b[col];
                }
            }
    } else if (bid < 400) {
        float (*t)[65] = (float(*)[65])smem;
        const int id = bid - 144;
        const int r0 = (id >> 4) * 64, c0 = (id & 15) * 64;
        const int tr = tid >> 4, tc = (tid & 15) * 4;
        #pragma unroll
        for (int i = 0; i < 4; ++i) {
            float4 v = *(const float4*)&A.V_w[(size_t)(r0 + tr + 16 * i) * ISZ + c0 + tc];
            t[tr + 16 * i][tc + 0] = v.x; t[tr + 16 * i][tc + 1] = v.y;
            t[tr + 16 * i][tc + 2] = v.z; t[tr + 16 * i][tc + 3] = v.w;
        }
        __syncthreads();
        #pragma unroll
        for (int i = 0; i < 4; ++i) {
            int rr = tr + 16 * i;
            float4 v = { t[tc + 0][rr], t[tc + 1][rr], t[tc + 2][rr], t[tc + 3][rr] };
            ushort4 h, l; split4(v, h, l);
            *(ushort4*)&A.Vth[(size_t)(c0 + rr) * ISZ + r0 + tc] = h;
            *(ushort4*)&A.Vtl[(size_t)(c0 + rr) * ISZ + r0 + tc] = l;
        }
    } else {
        const int id = bid - 400;
        const int c = tid << 2;
        #pragma unroll
        for (int r = 0; r < 8; ++r) {
            int row = id * 8 + r;
            float4 v = *(const float4*)&A.enc_w[(size_t)row * 2048 + c];
            ushort4 o = { f2bf(v.x), f2bf(v.y), f2bf(v.z), f2bf(v.w) };
            *(ushort4*)&A.encb[(size_t)row * ISZ + c] = o;
        }
    }
}

// ===========================================================================
// k_uv (128 blocks): uv += (U_b + sum Upart) @ V  (hi/lo 3-pass, split-K 8,
// atomic into memset-zero uv) — R5-verified path
// ===========================================================================
__global__ __launch_bounds__(TPB)
void k_uv(Args A)
{
    __shared__ __align__(16) unsigned char smem[32768];
    const int tid = threadIdx.x;
    const int bid = blockIdx.x;
    const int wid = tid >> 6, lane = tid & 63;
    const int s = bid >> 4, n0 = (bid & 15) * 64;
    const int kbeg = s * 128;
    const int srow = lane >> 3, sbyte = (lane & 7) << 4;
    const int swz = sbyte ^ (srow << 4);

    f32x4 acc[2][2] = {};
    for (int kt = 0; kt < 2; ++kt) {
        const int kk = kbeg + kt * 64;
        const int kbyte = kk * 2;
        #pragma unroll
        for (int i = 0; i < 2; ++i) {
            int r = wid * 8 + i * 32 + srow;
            size_t gb = (size_t)(n0 + r) * 2048 + kbyte + swz;
            gld_lds16((const char*)A.Vth + gb, (void*)(smem + 16384 + wid * 1024 + i * 4096));
            gld_lds16((const char*)A.Vtl + gb, (void*)(smem + 24576 + wid * 1024 + i * 4096));
        }
        stage_A_uv(A.Upart, A.U_b, kk, smem, smem + 8192, tid);
        __syncthreads();
        comp_hl(smem, acc, tid);
        __syncthreads();
    }
    const int wr = wid >> 1, wc = wid & 1;
    const int cl = lane & 15, rg = lane >> 4;
    #pragma unroll
    for (int m = 0; m < 2; ++m)
        #pragma unroll
        for (int n = 0; n < 2; ++n) {
            int col = n0 + wc * 32 + n * 16 + cl;
            #pragma unroll
            for (int j = 0; j < 4; ++j) {
                int row = wr * 32 + m * 16 + rg * 4 + j;
                atomicAdd(&A.uv[(size_t)row * ISZ + col], acc[m][n][j]);
            }
        }
}

// ===========================================================================
// k_attn (1280 blocks): logits + softmax + pool, wemb in registers (verified)
// ===========================================================================
__global__ __launch_bounds__(TPB)
void k_attn(Args A)
{
    __shared__ float red[16][4];
    __shared__ float att[16];
    const int t = blockIdx.x;
    const int b = t / NL;
    const int tid = threadIdx.x;
    const int lane = tid & 63, wid = tid >> 6;

    const float* w = A.wemb + (size_t)t * NM * ISZ;
    const int j0 = tid << 2;
    float4 u4 = *(const float4*)&A.uv[(size_t)b * ISZ + j0];

    float4 wv[NM];
    float part[NM];
    #pragma unroll
    for (int m = 0; m < NM; ++m) {
        wv[m] = *(const float4*)&w[m * ISZ + j0];
        part[m] = wv[m].x * u4.x + wv[m].y * u4.y + wv[m].z * u4.z + wv[m].w * u4.w;
    }
    #pragma unroll
    for (int m = 0; m < NM; ++m) {
        float v = part[m];
        #pragma unroll
        for (int off = 32; off > 0; off >>= 1) v += __shfl_down(v, off, 64);
        if (lane == 0) red[m][wid] = v;
    }
    __syncthreads();
    if (tid < NM) att[tid] = red[tid][0] + red[tid][1] + red[tid][2] + red[tid][3];
    __syncthreads();

    float mx = att[0];
    #pragma unroll
    for (int m = 1; m < NM; ++m) mx = fmaxf(mx, att[m]);
    float p[NM], sm = 0.0f;
    #pragma unroll
    for (int m = 0; m < NM; ++m) { p[m] = __expf(att[m] - mx); sm += p[m]; }
    float inv = 1.0f / sm;

    float4 acc = {0.0f, 0.0f, 0.0f, 0.0f};
    #pragma unroll
    for (int m = 0; m < NM; ++m) {
        float pm = p[m] * inv;
        acc.x += pm * wv[m].x; acc.y += pm * wv[m].y;
        acc.z += pm * wv[m].z; acc.w += pm * wv[m].w;
    }
    ushort4 o;
    o.x = f2bf(acc.x); o.y = f2bf(acc.y); o.z = f2bf(acc.z); o.w = f2bf(acc.w);
    *(ushort4*)&A.pooledb[(size_t)t * ISZ + j0] = o;
}

// ===========================================================================
// k_encln (80 blocks): fused encoder GEMM + LayerNorm.
// Block = 16 output rows x all 1024 cols. 4 waves; wave w owns cols
// [w*256, (w+1)*256) as 16 n-tiles of 16. A (pooled) LDS-staged (swizzled);
// B (encb, 2MB L2-hot) read as MFMA fragments straight from global.
// Epilogue: += cenc, per-row LN (shfl + LDS cross-wave reduce), write out.
// ===========================================================================
__global__ __launch_bounds__(TPB)
void k_encln(Args A)
{
    __shared__ __align__(16) unsigned char smemA[2048];      // 16 rows x 128 B
    __shared__ float reds[16][4], reds2[16][4];
    __shared__ float lmu[16], lrs[16];

    const int tid = threadIdx.x, wid = tid >> 6, lane = tid & 63;
    const int m0 = blockIdx.x * 16;
    const int n0w = wid * 256;
    const int ln = lane & 15, kb = lane >> 4;
    const int rg = lane >> 4;                                 // acc row group
    const int srow = lane >> 3;
    const int swz = ((lane & 7) << 4) ^ ((srow & 7) << 4);

    const char* Ab = (const char*)A.pooledb;
    const char* Bb = (const char*)A.encb;

    f32x4 acc[16] = {};

    for (int kt = 0; kt < 16; ++kt) {
        // stage A tile: wave 0 -> rows 0-7, wave 1 -> rows 8-15
        if (wid < 2) {
            gld_lds16(Ab + ((size_t)(m0 + wid * 8 + srow) * ISZ) * 2 + kt * 128 + swz,
                      (void*)(smemA + wid * 1024));
        }
        __syncthreads();   // drains vmcnt; A tile visible to all waves

        #pragma unroll
        for (int ks = 0; ks < 2; ++ks) {
            const int cb = ks * 64 + kb * 16;
            bf16x8 a = *(const bf16x8*)(smemA + ln * 128 + (cb ^ ((ln & 7) << 4)));
            #pragma unroll
            for (int h = 0; h < 2; ++h) {
                bf16x8 bfr[8];
                #pragma unroll
                for (int q = 0; q < 8; ++q) {
                    int rbg = n0w + (h * 8 + q) * 16 + ln;
                    bfr[q] = *(const bf16x8*)(Bb + (size_t)rbg * 2048 + kt * 128 + cb);
                }
                #pragma unroll
                for (int q = 0; q < 8; ++q)
                    acc[h * 8 + q] = __builtin_amdgcn_mfma_f32_16x16x32_bf16(a, bfr[q], acc[h * 8 + q], 0, 0, 0);
            }
        }
        __syncthreads();   // all waves done with A tile before restage
    }

    // ---- epilogue: + cenc, row partial sums ----
    float s[4] = {0.f, 0.f, 0.f, 0.f}, s2[4] = {0.f, 0.f, 0.f, 0.f};
    #pragma unroll
    for (int nt = 0; nt < 16; ++nt) {
        int col = n0w + nt * 16 + ln;
        #pragma unroll
        for (int j = 0; j < 4; ++j) {
            int rowg = m0 + rg * 4 + j;
            float v = acc[nt][j] + A.cenc[(size_t)(rowg / NL) * ISZ + col];
            acc[nt][j] = v;
            s[j] += v; s2[j] += v * v;
        }
    }
    // reduce across the 16 lanes of each rg group (masks < 16 stay in-group)
    #pragma unroll
    for (int j = 0; j < 4; ++j) {
        #pragma unroll
        for (int mk = 1; mk < 16; mk <<= 1) {
            s[j]  += __shfl_xor(s[j],  mk, 64);
            s2[j] += __shfl_xor(s2[j], mk, 64);
        }
    }
    if (ln == 0) {
        #pragma unroll
        for (int j = 0; j < 4; ++j) {
            reds[rg * 4 + j][wid]  = s[j];
            reds2[rg * 4 + j][wid] = s2[j];
        }
    }
    __syncthreads();
    if (tid < 16) {
        float S  = reds[tid][0]  + reds[tid][1]  + reds[tid][2]  + reds[tid][3];
        float S2 = reds2[tid][0] + reds2[tid][1] + reds2[tid][2] + reds2[tid][3];
        float mu  = S / ISZ;
        float var = S2 / ISZ - mu * mu;
        lmu[tid] = mu;
        lrs[tid] = rsqrtf(var + 1e-12f);
    }
    __syncthreads();

    #pragma unroll
    for (int nt = 0; nt < 16; ++nt) {
        int col = n0w + nt * 16 + ln;
        float g  = A.gamma[col];
        float be = A.beta[col];
        #pragma unroll
        for (int j = 0; j < 4; ++j) {
            int rl = rg * 4 + j;
            int rowg = m0 + rl;
            A.out[(size_t)rowg * ISZ + col] = g * (acc[nt][j] - lmu[rl]) * lrs[rl] + be;
        }
    }
}

// ---------------------------------------------------------------------------
extern "C" void kernel_launch(void* const* d_in, const int* in_sizes, int n_in,
                              void* d_out, int out_size, void* d_ws, size_t ws_size,
                              hipStream_t stream)
{
    Args A;
    A.ctx   = (const float*)d_in[0];
    A.wemb  = (const float*)d_in[1];
    // d_in[2] l_hpu, d_in[3] l_hs: constant (16, 20) -> unused
    A.U_w   = (const float*)d_in[4];
    A.U_b   = (const float*)d_in[5];
    A.V_w   = (const float*)d_in[6];
    // d_in[7] V_b: constant logit offset per header, cancels in softmax
    A.enc_w = (const float*)d_in[8];
    A.enc_b = (const float*)d_in[9];
    A.gamma = (const float*)d_in[10];
    A.beta  = (const float*)d_in[11];
    A.out   = (float*)d_out;

    float* ws = (float*)d_ws;
    A.uv    = ws;                                    // 64*1024 f32  (memset 0)
    A.Upart = ws + NB * ISZ;                         // 8*64*1024 f32
    A.cenc  = A.Upart + 8 * NB * ISZ;                // 64*1024 f32
    unsigned short* p = (unsigned short*)(A.cenc + NB * ISZ);
    A.Vth     = p;  p += ISZ * ISZ;                  // V^T hi
    A.Vtl     = p;  p += ISZ * ISZ;                  // V^T lo
    A.encb    = p;  p += ISZ * ISZ;                  // enc_w[:, :1024] bf16
    A.pooledb = p;                                   // 1280*1024 bf16

    hipMemsetAsync(A.uv, 0, (size_t)NB * ISZ * sizeof(float), stream);

    k_prep <<<528, TPB, 0, stream>>>(A);
    k_uv   <<<128, TPB, 0, stream>>>(A);
    k_attn <<<NT,  TPB, 0, stream>>>(A);
    k_encln<<<80,  TPB, 0, stream>>>(A);
}

// Round 12
// 73.115 us; speedup vs baseline: 3.6486x; 1.7142x over previous
//
#include <hip/hip_runtime.h>
#include <math.h>

#define TPB 256

constexpr int ISZ = 1024;   // feature dim
constexpr int NB  = 64;     // batch
constexpr int NL  = 20;     // headers per example
constexpr int NM  = 16;     // tokens per header
constexpr int NT  = NB * NL; // 1280 header-units

typedef __attribute__((ext_vector_type(8))) short  bf16x8;
typedef __attribute__((ext_vector_type(4))) float  f32x4;

struct Args {
    const float *ctx, *wemb, *U_w, *U_b, *V_w, *enc_w, *enc_b, *gamma, *beta;
    float *uv, *Upart, *cenc, *out;
    unsigned short *Vth, *Vtl, *encb, *pooledb;
};

__device__ __forceinline__ unsigned short f2bf(float x) {
    unsigned int u = __builtin_bit_cast(unsigned int, x);
    unsigned int r = (u + 0x7fff + ((u >> 16) & 1)) >> 16;   // RNE
    return (unsigned short)r;
}
__device__ __forceinline__ float bf2f(unsigned short h) {
    unsigned int u = ((unsigned int)h) << 16;
    return __builtin_bit_cast(float, u);
}
__device__ __forceinline__ void split4(float4 v, ushort4& h, ushort4& l) {
    h.x = f2bf(v.x); l.x = f2bf(v.x - bf2f(h.x));
    h.y = f2bf(v.y); l.y = f2bf(v.y - bf2f(h.y));
    h.z = f2bf(v.z); l.z = f2bf(v.z - bf2f(h.z));
    h.w = f2bf(v.w); l.w = f2bf(v.w - bf2f(h.w));
}
__device__ __forceinline__ void gld_lds16(const void* g, void* l) {
    __builtin_amdgcn_global_load_lds(
        (const __attribute__((address_space(1))) unsigned int*)g,
        (__attribute__((address_space(3))) unsigned int*)l, 16, 0, 0);
}

// ---------------------------------------------------------------------------
// LDS 64x64 bf16 tiles (8 KB each): Ah=+0, Al=+8K, Bh=+16K, Bl=+24K
// mapping: LDS[row][byte ^ ((row&7)<<4)] (128 B rows) — matches frag reads
// ---------------------------------------------------------------------------
__device__ __forceinline__ void stage_hl(const float* __restrict__ src, int ld,
                                         int kbeg, unsigned char* ldsH,
                                         unsigned char* ldsL, int tid)
{
    #pragma unroll
    for (int r = 0; r < 4; ++r) {
        int idx = r * 256 + tid;
        int row = idx >> 4, cg4 = (idx & 15) << 2;
        float4 v = *(const float4*)&src[(size_t)row * ld + kbeg + cg4];
        ushort4 h, l; split4(v, h, l);
        int boff = row * 128 + ((cg4 << 1) ^ ((row & 7) << 4));
        *(ushort4*)(ldsH + boff) = h;
        *(ushort4*)(ldsL + boff) = l;
    }
}
__device__ __forceinline__ void stage_h(const float* __restrict__ src, int ld,
                                        int kbeg, unsigned char* ldsH, int tid)
{
    #pragma unroll
    for (int r = 0; r < 4; ++r) {
        int idx = r * 256 + tid;
        int row = idx >> 4, cg4 = (idx & 15) << 2;
        float4 v = *(const float4*)&src[(size_t)row * ld + kbeg + cg4];
        ushort4 h = { f2bf(v.x), f2bf(v.y), f2bf(v.z), f2bf(v.w) };
        int boff = row * 128 + ((cg4 << 1) ^ ((row & 7) << 4));
        *(ushort4*)(ldsH + boff) = h;
    }
}
// A-stage for uv: wenc_u[row][k] = U_b[k] + sum_s Upart[s][row][k], hi/lo
__device__ __forceinline__ void stage_A_uv(const float* __restrict__ Upart,
                                           const float* __restrict__ U_b,
                                           int kbeg, unsigned char* ldsH,
                                           unsigned char* ldsL, int tid)
{
    #pragma unroll
    for (int r = 0; r < 4; ++r) {
        int idx = r * 256 + tid;
        int row = idx >> 4, cg4 = (idx & 15) << 2;
        int k = kbeg + cg4;
        float4 v = *(const float4*)&U_b[k];
        #pragma unroll
        for (int s = 0; s < 8; ++s) {
            float4 u = *(const float4*)&Upart[(size_t)(s * 64 + row) * ISZ + k];
            v.x += u.x; v.y += u.y; v.z += u.z; v.w += u.w;
        }
        ushort4 h, l; split4(v, h, l);
        int boff = row * 128 + ((cg4 << 1) ^ ((row & 7) << 4));
        *(ushort4*)(ldsH + boff) = h;
        *(ushort4*)(ldsL + boff) = l;
    }
}

__device__ __forceinline__ void comp_hl(const unsigned char* lds, f32x4 acc[2][2], int tid)
{
    const int wid = tid >> 6, lane = tid & 63;
    const int ln = lane & 15, kb = lane >> 4;
    const int wr = wid >> 1, wc = wid & 1;
    #pragma unroll
    for (int ks = 0; ks < 2; ++ks) {
        const int cb = ks * 64 + kb * 16;
        bf16x8 ah[2], al[2], bh[2], bl[2];
        #pragma unroll
        for (int m = 0; m < 2; ++m) {
            int ra = wr * 32 + m * 16 + ln;
            int off = ra * 128 + (cb ^ ((ra & 7) << 4));
            ah[m] = *(const bf16x8*)(lds + off);
            al[m] = *(const bf16x8*)(lds + 8192 + off);
        }
        #pragma unroll
        for (int n = 0; n < 2; ++n) {
            int rb = wc * 32 + n * 16 + ln;
            int off = rb * 128 + (cb ^ ((rb & 7) << 4));
            bh[n] = *(const bf16x8*)(lds + 16384 + off);
            bl[n] = *(const bf16x8*)(lds + 24576 + off);
        }
        #pragma unroll
        for (int m = 0; m < 2; ++m)
            #pragma unroll
            for (int n = 0; n < 2; ++n) {
                acc[m][n] = __builtin_amdgcn_mfma_f32_16x16x32_bf16(ah[m], bh[n], acc[m][n], 0, 0, 0);
                acc[m][n] = __builtin_amdgcn_mfma_f32_16x16x32_bf16(ah[m], bl[n], acc[m][n], 0, 0, 0);
                acc[m][n] = __builtin_amdgcn_mfma_f32_16x16x32_bf16(al[m], bh[n], acc[m][n], 0, 0, 0);
            }
    }
}
__device__ __forceinline__ void comp_h(const unsigned char* lds, f32x4 acc[2][2], int tid)
{
    const int wid = tid >> 6, lane = tid & 63;
    const int ln = lane & 15, kb = lane >> 4;
    const int wr = wid >> 1, wc = wid & 1;
    #pragma unroll
    for (int ks = 0; ks < 2; ++ks) {
        const int cb = ks * 64 + kb * 16;
        bf16x8 ah[2], bh[2];
        #pragma unroll
        for (int m = 0; m < 2; ++m) {
            int ra = wr * 32 + m * 16 + ln;
            ah[m] = *(const bf16x8*)(lds + ra * 128 + (cb ^ ((ra & 7) << 4)));
        }
        #pragma unroll
        for (int n = 0; n < 2; ++n) {
            int rb = wc * 32 + n * 16 + ln;
            bh[n] = *(const bf16x8*)(lds + 16384 + rb * 128 + (cb ^ ((rb & 7) << 4)));
        }
        #pragma unroll
        for (int m = 0; m < 2; ++m)
            #pragma unroll
            for (int n = 0; n < 2; ++n)
                acc[m][n] = __builtin_amdgcn_mfma_f32_16x16x32_bf16(ah[m], bh[n], acc[m][n], 0, 0, 0);
    }
}

// ===========================================================================
// k_prep (544 blocks, fully independent):
//  [0,128)   Upart[s] = ctx @ U_w^T (hi/lo, k-chunk s)
//  [128,144) cenc = ctx @ enc_w[:,1024:]^T + enc_b  (full-K direct)
//  [144,400) V^T 64x64 -> Vth/Vtl (hi/lo)
//  [400,528) encb: enc_w[:, :1024] -> bf16 (8 rows/block)
//  [528,544) uv = 0  (consumed by k_uv's atomics NEXT launch)
// ===========================================================================
__global__ __launch_bounds__(TPB)
void k_prep(Args A)
{
    __shared__ __align__(16) unsigned char smem[32768];
    const int bid = blockIdx.x, tid = threadIdx.x;
    const int wid = tid >> 6, lane = tid & 63;
    const int wr = wid >> 1, wc = wid & 1;
    const int cl = lane & 15, rg = lane >> 4;

    if (bid < 128) {
        const int s = bid >> 4, n0 = (bid & 15) * 64;
        const int kbeg = s * 128;
        f32x4 acc[2][2] = {};
        for (int kt = 0; kt < 2; ++kt) {
            const int kk = kbeg + kt * 64;
            stage_hl(A.ctx, ISZ, kk, smem, smem + 8192, tid);
            stage_hl(A.U_w + (size_t)n0 * ISZ, ISZ, kk, smem + 16384, smem + 24576, tid);
            __syncthreads();
            comp_hl(smem, acc, tid);
            __syncthreads();
        }
        #pragma unroll
        for (int m = 0; m < 2; ++m)
            #pragma unroll
            for (int n = 0; n < 2; ++n) {
                int col = n0 + wc * 32 + n * 16 + cl;
                #pragma unroll
                for (int j = 0; j < 4; ++j) {
                    int row = wr * 32 + m * 16 + rg * 4 + j;
                    A.Upart[(size_t)(s * 64 + row) * ISZ + col] = acc[m][n][j];
                }
            }
    } else if (bid < 144) {
        const int n0 = (bid - 128) * 64;
        f32x4 acc[2][2] = {};
        for (int kt = 0; kt < 16; ++kt) {
            const int kk = kt * 64;
            stage_h(A.ctx, ISZ, kk, smem, tid);
            stage_h(A.enc_w + (size_t)n0 * 2048 + 1024, 2048, kk, smem + 16384, tid);
            __syncthreads();
            comp_h(smem, acc, tid);
            __syncthreads();
        }
        #pragma unroll
        for (int m = 0; m < 2; ++m)
            #pragma unroll
            for (int n = 0; n < 2; ++n) {
                int col = n0 + wc * 32 + n * 16 + cl;
                #pragma unroll
                for (int j = 0; j < 4; ++j) {
                    int row = wr * 32 + m * 16 + rg * 4 + j;
                    A.cenc[(size_t)row * ISZ + col] = acc[m][n][j] + A.enc_b[col];
                }
            }
    } else if (bid < 400) {
        float (*t)[65] = (float(*)[65])smem;
        const int id = bid - 144;
        const int r0 = (id >> 4) * 64, c0 = (id & 15) * 64;
        const int tr = tid >> 4, tc = (tid & 15) * 4;
        #pragma unroll
        for (int i = 0; i < 4; ++i) {
            float4 v = *(const float4*)&A.V_w[(size_t)(r0 + tr + 16 * i) * ISZ + c0 + tc];
            t[tr + 16 * i][tc + 0] = v.x; t[tr + 16 * i][tc + 1] = v.y;
            t[tr + 16 * i][tc + 2] = v.z; t[tr + 16 * i][tc + 3] = v.w;
        }
        __syncthreads();
        #pragma unroll
        for (int i = 0; i < 4; ++i) {
            int rr = tr + 16 * i;
            float4 v = { t[tc + 0][rr], t[tc + 1][rr], t[tc + 2][rr], t[tc + 3][rr] };
            ushort4 h, l; split4(v, h, l);
            *(ushort4*)&A.Vth[(size_t)(c0 + rr) * ISZ + r0 + tc] = h;
            *(ushort4*)&A.Vtl[(size_t)(c0 + rr) * ISZ + r0 + tc] = l;
        }
    } else if (bid < 528) {
        const int id = bid - 400;
        const int c = tid << 2;
        #pragma unroll
        for (int r = 0; r < 8; ++r) {
            int row = id * 8 + r;
            float4 v = *(const float4*)&A.enc_w[(size_t)row * 2048 + c];
            ushort4 o = { f2bf(v.x), f2bf(v.y), f2bf(v.z), f2bf(v.w) };
            *(ushort4*)&A.encb[(size_t)row * ISZ + c] = o;
        }
    } else {
        const int id = bid - 528;              // 16 blocks zero 64K floats
        float4 z = {0.f, 0.f, 0.f, 0.f};
        #pragma unroll
        for (int r = 0; r < 4; ++r) {
            int i4 = ((id * TPB + tid) * 4 + r) * 4;
            *(float4*)&A.uv[i4] = z;
        }
    }
}

// ===========================================================================
// k_uv (128 blocks): uv += (U_b + sum Upart) @ V  (hi/lo 3-pass, split-K 8,
// atomic into prep-zeroed uv) — R5-verified path
// ===========================================================================
__global__ __launch_bounds__(TPB)
void k_uv(Args A)
{
    __shared__ __align__(16) unsigned char smem[32768];
    const int tid = threadIdx.x;
    const int bid = blockIdx.x;
    const int wid = tid >> 6, lane = tid & 63;
    const int s = bid >> 4, n0 = (bid & 15) * 64;
    const int kbeg = s * 128;
    const int srow = lane >> 3, sbyte = (lane & 7) << 4;
    const int swz = sbyte ^ (srow << 4);

    f32x4 acc[2][2] = {};
    for (int kt = 0; kt < 2; ++kt) {
        const int kk = kbeg + kt * 64;
        const int kbyte = kk * 2;
        #pragma unroll
        for (int i = 0; i < 2; ++i) {
            int r = wid * 8 + i * 32 + srow;
            size_t gb = (size_t)(n0 + r) * 2048 + kbyte + swz;
            gld_lds16((const char*)A.Vth + gb, (void*)(smem + 16384 + wid * 1024 + i * 4096));
            gld_lds16((const char*)A.Vtl + gb, (void*)(smem + 24576 + wid * 1024 + i * 4096));
        }
        stage_A_uv(A.Upart, A.U_b, kk, smem, smem + 8192, tid);
        __syncthreads();
        comp_hl(smem, acc, tid);
        __syncthreads();
    }
    const int wr = wid >> 1, wc = wid & 1;
    const int cl = lane & 15, rg = lane >> 4;
    #pragma unroll
    for (int m = 0; m < 2; ++m)
        #pragma unroll
        for (int n = 0; n < 2; ++n) {
            int col = n0 + wc * 32 + n * 16 + cl;
            #pragma unroll
            for (int j = 0; j < 4; ++j) {
                int row = wr * 32 + m * 16 + rg * 4 + j;
                atomicAdd(&A.uv[(size_t)row * ISZ + col], acc[m][n][j]);
            }
        }
}

// ===========================================================================
// k_attn (1280 blocks): logits + softmax + pool, wemb in registers (verified)
// ===========================================================================
__global__ __launch_bounds__(TPB)
void k_attn(Args A)
{
    __shared__ float red[16][4];
    __shared__ float att[16];
    const int t = blockIdx.x;
    const int b = t / NL;
    const int tid = threadIdx.x;
    const int lane = tid & 63, wid = tid >> 6;

    const float* w = A.wemb + (size_t)t * NM * ISZ;
    const int j0 = tid << 2;
    float4 u4 = *(const float4*)&A.uv[(size_t)b * ISZ + j0];

    float4 wv[NM];
    float part[NM];
    #pragma unroll
    for (int m = 0; m < NM; ++m) {
        wv[m] = *(const float4*)&w[m * ISZ + j0];
        part[m] = wv[m].x * u4.x + wv[m].y * u4.y + wv[m].z * u4.z + wv[m].w * u4.w;
    }
    #pragma unroll
    for (int m = 0; m < NM; ++m) {
        float v = part[m];
        #pragma unroll
        for (int off = 32; off > 0; off >>= 1) v += __shfl_down(v, off, 64);
        if (lane == 0) red[m][wid] = v;
    }
    __syncthreads();
    if (tid < NM) att[tid] = red[tid][0] + red[tid][1] + red[tid][2] + red[tid][3];
    __syncthreads();

    float mx = att[0];
    #pragma unroll
    for (int m = 1; m < NM; ++m) mx = fmaxf(mx, att[m]);
    float p[NM], sm = 0.0f;
    #pragma unroll
    for (int m = 0; m < NM; ++m) { p[m] = __expf(att[m] - mx); sm += p[m]; }
    float inv = 1.0f / sm;

    float4 acc = {0.0f, 0.0f, 0.0f, 0.0f};
    #pragma unroll
    for (int m = 0; m < NM; ++m) {
        float pm = p[m] * inv;
        acc.x += pm * wv[m].x; acc.y += pm * wv[m].y;
        acc.z += pm * wv[m].z; acc.w += pm * wv[m].w;
    }
    ushort4 o;
    o.x = f2bf(acc.x); o.y = f2bf(acc.y); o.z = f2bf(acc.z); o.w = f2bf(acc.w);
    *(ushort4*)&A.pooledb[(size_t)t * ISZ + j0] = o;
}

// ===========================================================================
// k_enc (160 blocks): BM=128, BN=64 MFMA GEMM (R2/R4/R5-verified body)
// out = pooled @ enc_w[:,:1024]^T + cenc[row/20]   (cenc includes enc_b)
// ===========================================================================
__global__ __launch_bounds__(TPB)
void k_enc(Args A)
{
    __shared__ __align__(16) unsigned char smem[24576];
    const int tid  = threadIdx.x;
    const int wid  = tid >> 6, lane = tid & 63;
    const int m0   = (blockIdx.x >> 4) * 128;
    const int n0   = (blockIdx.x & 15) * 64;
    const int ln   = lane & 15, kb = lane >> 4;
    const int wr   = wid >> 1, wc = wid & 1;
    const int srow = lane >> 3, sbyte = (lane & 7) << 4;
    const int swz  = sbyte ^ (srow << 4);

    f32x4 acc[4][2] = {};
    const char* Abase = (const char*)A.pooledb;
    const char* Bbase = (const char*)A.encb;

    for (int kt = 0; kt < 16; ++kt) {
        const int kbyte = kt * 128;
        #pragma unroll
        for (int i = 0; i < 4; ++i) {
            int r = wid * 8 + i * 32 + srow;
            gld_lds16(Abase + ((size_t)(m0 + r) * ISZ) * 2 + kbyte + swz,
                      (void*)(smem + wid * 1024 + i * 4096));
        }
        #pragma unroll
        for (int i = 0; i < 2; ++i) {
            int r = wid * 8 + i * 32 + srow;
            gld_lds16(Bbase + ((size_t)(n0 + r) * ISZ) * 2 + kbyte + swz,
                      (void*)(smem + 16384 + wid * 1024 + i * 4096));
        }
        __syncthreads();
        #pragma unroll
        for (int ks = 0; ks < 2; ++ks) {
            const int cb = (ks * 64 + kb * 16);
            bf16x8 a[4], b[2];
            #pragma unroll
            for (int m = 0; m < 4; ++m) {
                int ra = wr * 64 + m * 16 + ln;
                a[m] = *(const bf16x8*)(smem + ra * 128 + (cb ^ ((ra & 7) << 4)));
            }
            #pragma unroll
            for (int n = 0; n < 2; ++n) {
                int rb = wc * 32 + n * 16 + ln;
                b[n] = *(const bf16x8*)(smem + 16384 + rb * 128 + (cb ^ ((rb & 7) << 4)));
            }
            #pragma unroll
            for (int m = 0; m < 4; ++m)
                #pragma unroll
                for (int n = 0; n < 2; ++n)
                    acc[m][n] = __builtin_amdgcn_mfma_f32_16x16x32_bf16(a[m], b[n], acc[m][n], 0, 0, 0);
        }
        __syncthreads();
    }

    const int cl = lane & 15, rg = lane >> 4;
    #pragma unroll
    for (int m = 0; m < 4; ++m) {
        #pragma unroll
        for (int n = 0; n < 2; ++n) {
            int col = n0 + wc * 32 + n * 16 + cl;
            #pragma unroll
            for (int j = 0; j < 4; ++j) {
                int row = m0 + wr * 64 + m * 16 + rg * 4 + j;
                A.out[(size_t)row * ISZ + col] = acc[m][n][j] + A.cenc[(size_t)(row / NL) * ISZ + col];
            }
        }
    }
}

// ===========================================================================
// k_ln (1280): TF-style LayerNorm in-place on out (verified)
// ===========================================================================
__global__ __launch_bounds__(TPB)
void k_ln(Args A)
{
    __shared__ float rs[4], rs2[4];
    __shared__ float mu_s, rstd_s;
    const int t = blockIdx.x;
    const int tid = threadIdx.x;
    const int lane = tid & 63, wid = tid >> 6;
    const int c = tid << 2;

    float4 v = *(const float4*)&A.out[(size_t)t * ISZ + c];
    float s  = v.x + v.y + v.z + v.w;
    float s2 = v.x * v.x + v.y * v.y + v.z * v.z + v.w * v.w;
    #pragma unroll
    for (int off = 32; off > 0; off >>= 1) {
        s  += __shfl_down(s, off, 64);
        s2 += __shfl_down(s2, off, 64);
    }
    if (lane == 0) { rs[wid] = s; rs2[wid] = s2; }
    __syncthreads();
    if (tid == 0) {
        float S  = rs[0] + rs[1] + rs[2] + rs[3];
        float S2 = rs2[0] + rs2[1] + rs2[2] + rs2[3];
        float m  = S / ISZ;
        float var = S2 / ISZ - m * m;
        mu_s  = m;
        rstd_s = rsqrtf(var + 1e-12f);
    }
    __syncthreads();
    const float mu = mu_s, rstd = rstd_s;
    float4 g  = *(const float4*)&A.gamma[c];
    float4 be = *(const float4*)&A.beta[c];
    float4 o;
    o.x = g.x * (v.x - mu) * rstd + be.x;
    o.y = g.y * (v.y - mu) * rstd + be.y;
    o.z = g.z * (v.z - mu) * rstd + be.z;
    o.w = g.w * (v.w - mu) * rstd + be.w;
    *(float4*)&A.out[(size_t)t * ISZ + c] = o;
}

// ---------------------------------------------------------------------------
extern "C" void kernel_launch(void* const* d_in, const int* in_sizes, int n_in,
                              void* d_out, int out_size, void* d_ws, size_t ws_size,
                              hipStream_t stream)
{
    Args A;
    A.ctx   = (const float*)d_in[0];
    A.wemb  = (const float*)d_in[1];
    // d_in[2] l_hpu, d_in[3] l_hs: constant (16, 20) -> unused
    A.U_w   = (const float*)d_in[4];
    A.U_b   = (const float*)d_in[5];
    A.V_w   = (const float*)d_in[6];
    // d_in[7] V_b: constant logit offset per header, cancels in softmax
    A.enc_w = (const float*)d_in[8];
    A.enc_b = (const float*)d_in[9];
    A.gamma = (const float*)d_in[10];
    A.beta  = (const float*)d_in[11];
    A.out   = (float*)d_out;

    float* ws = (float*)d_ws;
    A.uv    = ws;                                    // 64*1024 f32  (zeroed in k_prep)
    A.Upart = ws + NB * ISZ;                         // 8*64*1024 f32
    A.cenc  = A.Upart + 8 * NB * ISZ;                // 64*1024 f32
    unsigned short* p = (unsigned short*)(A.cenc + NB * ISZ);
    A.Vth     = p;  p += ISZ * ISZ;                  // V^T hi
    A.Vtl     = p;  p += ISZ * ISZ;                  // V^T lo
    A.encb    = p;  p += ISZ * ISZ;                  // enc_w[:, :1024] bf16
    A.pooledb = p;                                   // 1280*1024 bf16

    k_prep<<<544, TPB, 0, stream>>>(A);
    k_uv  <<<128, TPB, 0, stream>>>(A);
    k_attn<<<NT,  TPB, 0, stream>>>(A);
    k_enc <<<160, TPB, 0, stream>>>(A);
    k_ln  <<<NT,  TPB, 0, stream>>>(A);
}

// Round 13
// 60.291 us; speedup vs baseline: 4.4246x; 1.2127x over previous
//
#include <hip/hip_runtime.h>
#include <math.h>

#define TPB 256

constexpr int ISZ = 1024;   // feature dim
constexpr int NB  = 64;     // batch
constexpr int NL  = 20;     // headers per example
constexpr int NM  = 16;     // tokens per header
constexpr int NT  = NB * NL; // 1280 header-units

typedef __attribute__((ext_vector_type(8))) short  bf16x8;
typedef __attribute__((ext_vector_type(4))) float  f32x4;

struct Args {
    const float *ctx, *wemb, *U_w, *U_b, *V_w, *enc_w, *enc_b, *gamma, *beta;
    float *uv, *Upart, *Cpart, *cenc, *out;
    unsigned short *Vth, *Vtl, *encb, *pooledb;
};

__device__ __forceinline__ unsigned short f2bf(float x) {
    unsigned int u = __builtin_bit_cast(unsigned int, x);
    unsigned int r = (u + 0x7fff + ((u >> 16) & 1)) >> 16;   // RNE
    return (unsigned short)r;
}
__device__ __forceinline__ float bf2f(unsigned short h) {
    unsigned int u = ((unsigned int)h) << 16;
    return __builtin_bit_cast(float, u);
}
__device__ __forceinline__ void split4(float4 v, ushort4& h, ushort4& l) {
    h.x = f2bf(v.x); l.x = f2bf(v.x - bf2f(h.x));
    h.y = f2bf(v.y); l.y = f2bf(v.y - bf2f(h.y));
    h.z = f2bf(v.z); l.z = f2bf(v.z - bf2f(h.z));
    h.w = f2bf(v.w); l.w = f2bf(v.w - bf2f(h.w));
}
__device__ __forceinline__ void gld_lds16(const void* g, void* l) {
    __builtin_amdgcn_global_load_lds(
        (const __attribute__((address_space(1))) unsigned int*)g,
        (__attribute__((address_space(3))) unsigned int*)l, 16, 0, 0);
}

// ---------------------------------------------------------------------------
// LDS 64x64 bf16 tiles (8 KB each): Ah=+0, Al=+8K, Bh=+16K, Bl=+24K
// mapping: LDS[row][byte ^ ((row&7)<<4)] (128 B rows) — matches frag reads
// ---------------------------------------------------------------------------
__device__ __forceinline__ void stage_hl(const float* __restrict__ src, int ld,
                                         int kbeg, unsigned char* ldsH,
                                         unsigned char* ldsL, int tid)
{
    #pragma unroll
    for (int r = 0; r < 4; ++r) {
        int idx = r * 256 + tid;
        int row = idx >> 4, cg4 = (idx & 15) << 2;
        float4 v = *(const float4*)&src[(size_t)row * ld + kbeg + cg4];
        ushort4 h, l; split4(v, h, l);
        int boff = row * 128 + ((cg4 << 1) ^ ((row & 7) << 4));
        *(ushort4*)(ldsH + boff) = h;
        *(ushort4*)(ldsL + boff) = l;
    }
}
__device__ __forceinline__ void stage_h(const float* __restrict__ src, int ld,
                                        int kbeg, unsigned char* ldsH, int tid)
{
    #pragma unroll
    for (int r = 0; r < 4; ++r) {
        int idx = r * 256 + tid;
        int row = idx >> 4, cg4 = (idx & 15) << 2;
        float4 v = *(const float4*)&src[(size_t)row * ld + kbeg + cg4];
        ushort4 h = { f2bf(v.x), f2bf(v.y), f2bf(v.z), f2bf(v.w) };
        int boff = row * 128 + ((cg4 << 1) ^ ((row & 7) << 4));
        *(ushort4*)(ldsH + boff) = h;
    }
}
// A-stage for uv: wenc_u[row][k] = U_b[k] + sum_s Upart[s][row][k], hi/lo
__device__ __forceinline__ void stage_A_uv(const float* __restrict__ Upart,
                                           const float* __restrict__ U_b,
                                           int kbeg, unsigned char* ldsH,
                                           unsigned char* ldsL, int tid)
{
    #pragma unroll
    for (int r = 0; r < 4; ++r) {
        int idx = r * 256 + tid;
        int row = idx >> 4, cg4 = (idx & 15) << 2;
        int k = kbeg + cg4;
        float4 v = *(const float4*)&U_b[k];
        #pragma unroll
        for (int s = 0; s < 8; ++s) {
            float4 u = *(const float4*)&Upart[(size_t)(s * 64 + row) * ISZ + k];
            v.x += u.x; v.y += u.y; v.z += u.z; v.w += u.w;
        }
        ushort4 h, l; split4(v, h, l);
        int boff = row * 128 + ((cg4 << 1) ^ ((row & 7) << 4));
        *(ushort4*)(ldsH + boff) = h;
        *(ushort4*)(ldsL + boff) = l;
    }
}

__device__ __forceinline__ void comp_hl(const unsigned char* lds, f32x4 acc[2][2], int tid)
{
    const int wid = tid >> 6, lane = tid & 63;
    const int ln = lane & 15, kb = lane >> 4;
    const int wr = wid >> 1, wc = wid & 1;
    #pragma unroll
    for (int ks = 0; ks < 2; ++ks) {
        const int cb = ks * 64 + kb * 16;
        bf16x8 ah[2], al[2], bh[2], bl[2];
        #pragma unroll
        for (int m = 0; m < 2; ++m) {
            int ra = wr * 32 + m * 16 + ln;
            int off = ra * 128 + (cb ^ ((ra & 7) << 4));
            ah[m] = *(const bf16x8*)(lds + off);
            al[m] = *(const bf16x8*)(lds + 8192 + off);
        }
        #pragma unroll
        for (int n = 0; n < 2; ++n) {
            int rb = wc * 32 + n * 16 + ln;
            int off = rb * 128 + (cb ^ ((rb & 7) << 4));
            bh[n] = *(const bf16x8*)(lds + 16384 + off);
            bl[n] = *(const bf16x8*)(lds + 24576 + off);
        }
        #pragma unroll
        for (int m = 0; m < 2; ++m)
            #pragma unroll
            for (int n = 0; n < 2; ++n) {
                acc[m][n] = __builtin_amdgcn_mfma_f32_16x16x32_bf16(ah[m], bh[n], acc[m][n], 0, 0, 0);
                acc[m][n] = __builtin_amdgcn_mfma_f32_16x16x32_bf16(ah[m], bl[n], acc[m][n], 0, 0, 0);
                acc[m][n] = __builtin_amdgcn_mfma_f32_16x16x32_bf16(al[m], bh[n], acc[m][n], 0, 0, 0);
            }
    }
}
__device__ __forceinline__ void comp_h(const unsigned char* lds, f32x4 acc[2][2], int tid)
{
    const int wid = tid >> 6, lane = tid & 63;
    const int ln = lane & 15, kb = lane >> 4;
    const int wr = wid >> 1, wc = wid & 1;
    #pragma unroll
    for (int ks = 0; ks < 2; ++ks) {
        const int cb = ks * 64 + kb * 16;
        bf16x8 ah[2], bh[2];
        #pragma unroll
        for (int m = 0; m < 2; ++m) {
            int ra = wr * 32 + m * 16 + ln;
            ah[m] = *(const bf16x8*)(lds + ra * 128 + (cb ^ ((ra & 7) << 4)));
        }
        #pragma unroll
        for (int n = 0; n < 2; ++n) {
            int rb = wc * 32 + n * 16 + ln;
            bh[n] = *(const bf16x8*)(lds + 16384 + rb * 128 + (cb ^ ((rb & 7) << 4)));
        }
        #pragma unroll
        for (int m = 0; m < 2; ++m)
            #pragma unroll
            for (int n = 0; n < 2; ++n)
                acc[m][n] = __builtin_amdgcn_mfma_f32_16x16x32_bf16(ah[m], bh[n], acc[m][n], 0, 0, 0);
    }
}

// ===========================================================================
// k_prep (656 blocks, fully independent, every branch <= 2 serial K-steps):
//  [0,128)   Upart[s] = ctx @ U_w^T (hi/lo, k-chunk s)
//  [128,256) Cpart[s] = ctx @ enc_w[:,1024:]^T (k-chunk s)
//  [256,512) V^T 64x64 -> Vth/Vtl (hi/lo)
//  [512,640) encb: enc_w[:, :1024] -> bf16 (8 rows/block)
//  [640,656) uv = 0  (consumed by k_mid atomics NEXT launch)
// ===========================================================================
__global__ __launch_bounds__(TPB)
void k_prep(Args A)
{
    __shared__ __align__(16) unsigned char smem[32768];
    const int bid = blockIdx.x, tid = threadIdx.x;
    const int wid = tid >> 6, lane = tid & 63;
    const int wr = wid >> 1, wc = wid & 1;
    const int cl = lane & 15, rg = lane >> 4;

    if (bid < 256) {
        const bool isU = (bid < 128);
        const int id = isU ? bid : bid - 128;
        const int s = id >> 4, n0 = (id & 15) * 64;
        const int kbeg = s * 128;
        f32x4 acc[2][2] = {};
        for (int kt = 0; kt < 2; ++kt) {
            const int kk = kbeg + kt * 64;
            if (isU) {
                stage_hl(A.ctx, ISZ, kk, smem, smem + 8192, tid);
                stage_hl(A.U_w + (size_t)n0 * ISZ, ISZ, kk, smem + 16384, smem + 24576, tid);
            } else {
                stage_h(A.ctx, ISZ, kk, smem, tid);
                stage_h(A.enc_w + (size_t)n0 * 2048 + 1024, 2048, kk, smem + 16384, tid);
            }
            __syncthreads();
            if (isU) comp_hl(smem, acc, tid);
            else     comp_h(smem, acc, tid);
            __syncthreads();
        }
        float* dst = isU ? A.Upart : A.Cpart;
        #pragma unroll
        for (int m = 0; m < 2; ++m)
            #pragma unroll
            for (int n = 0; n < 2; ++n) {
                int col = n0 + wc * 32 + n * 16 + cl;
                #pragma unroll
                for (int j = 0; j < 4; ++j) {
                    int row = wr * 32 + m * 16 + rg * 4 + j;
                    dst[(size_t)(s * 64 + row) * ISZ + col] = acc[m][n][j];
                }
            }
    } else if (bid < 512) {
        float (*t)[65] = (float(*)[65])smem;
        const int id = bid - 256;
        const int r0 = (id >> 4) * 64, c0 = (id & 15) * 64;
        const int tr = tid >> 4, tc = (tid & 15) * 4;
        #pragma unroll
        for (int i = 0; i < 4; ++i) {
            float4 v = *(const float4*)&A.V_w[(size_t)(r0 + tr + 16 * i) * ISZ + c0 + tc];
            t[tr + 16 * i][tc + 0] = v.x; t[tr + 16 * i][tc + 1] = v.y;
            t[tr + 16 * i][tc + 2] = v.z; t[tr + 16 * i][tc + 3] = v.w;
        }
        __syncthreads();
        #pragma unroll
        for (int i = 0; i < 4; ++i) {
            int rr = tr + 16 * i;
            float4 v = { t[tc + 0][rr], t[tc + 1][rr], t[tc + 2][rr], t[tc + 3][rr] };
            ushort4 h, l; split4(v, h, l);
            *(ushort4*)&A.Vth[(size_t)(c0 + rr) * ISZ + r0 + tc] = h;
            *(ushort4*)&A.Vtl[(size_t)(c0 + rr) * ISZ + r0 + tc] = l;
        }
    } else if (bid < 640) {
        const int id = bid - 512;
        const int c = tid << 2;
        #pragma unroll
        for (int r = 0; r < 8; ++r) {
            int row = id * 8 + r;
            float4 v = *(const float4*)&A.enc_w[(size_t)row * 2048 + c];
            ushort4 o = { f2bf(v.x), f2bf(v.y), f2bf(v.z), f2bf(v.w) };
            *(ushort4*)&A.encb[(size_t)row * ISZ + c] = o;
        }
    } else {
        const int id = bid - 640;              // 16 blocks zero 64K floats
        float4 z = {0.f, 0.f, 0.f, 0.f};
        #pragma unroll
        for (int r = 0; r < 4; ++r) {
            int i4 = ((id * TPB + tid) * 4 + r) * 4;
            *(float4*)&A.uv[i4] = z;
        }
    }
}

// ===========================================================================
// k_mid (144 blocks):
//  [0,128)   uv += (U_b + sum Upart) @ V  (hi/lo 3-pass, split-K 8, atomic
//            into prep-zeroed uv)  — R12-verified body
//  [128,144) cenc = sum_s Cpart[s] + enc_b (elementwise) — R9-verified body
// ===========================================================================
__global__ __launch_bounds__(TPB)
void k_mid(Args A)
{
    __shared__ __align__(16) unsigned char smem[32768];
    const int bid = blockIdx.x, tid = threadIdx.x;
    const int wid = tid >> 6, lane = tid & 63;

    if (bid < 128) {
        const int s = bid >> 4, n0 = (bid & 15) * 64;
        const int kbeg = s * 128;
        const int srow = lane >> 3, sbyte = (lane & 7) << 4;
        const int swz = sbyte ^ (srow << 4);
        f32x4 acc[2][2] = {};
        for (int kt = 0; kt < 2; ++kt) {
            const int kk = kbeg + kt * 64;
            const int kbyte = kk * 2;
            #pragma unroll
            for (int i = 0; i < 2; ++i) {
                int r = wid * 8 + i * 32 + srow;
                size_t gb = (size_t)(n0 + r) * 2048 + kbyte + swz;
                gld_lds16((const char*)A.Vth + gb, (void*)(smem + 16384 + wid * 1024 + i * 4096));
                gld_lds16((const char*)A.Vtl + gb, (void*)(smem + 24576 + wid * 1024 + i * 4096));
            }
            stage_A_uv(A.Upart, A.U_b, kk, smem, smem + 8192, tid);
            __syncthreads();
            comp_hl(smem, acc, tid);
            __syncthreads();
        }
        const int wr = wid >> 1, wc = wid & 1;
        const int cl = lane & 15, rg = lane >> 4;
        #pragma unroll
        for (int m = 0; m < 2; ++m)
            #pragma unroll
            for (int n = 0; n < 2; ++n) {
                int col = n0 + wc * 32 + n * 16 + cl;
                #pragma unroll
                for (int j = 0; j < 4; ++j) {
                    int row = wr * 32 + m * 16 + rg * 4 + j;
                    atomicAdd(&A.uv[(size_t)row * ISZ + col], acc[m][n][j]);
                }
            }
    } else {
        const int row0 = (bid - 128) * 4;
        const int c = tid << 2;
        #pragma unroll
        for (int r = 0; r < 4; ++r) {
            int row = row0 + r;
            float4 v = *(const float4*)&A.enc_b[c];
            #pragma unroll
            for (int s = 0; s < 8; ++s) {
                float4 u = *(const float4*)&A.Cpart[(size_t)(s * 64 + row) * ISZ + c];
                v.x += u.x; v.y += u.y; v.z += u.z; v.w += u.w;
            }
            *(float4*)&A.cenc[(size_t)row * ISZ + c] = v;
        }
    }
}

// ===========================================================================
// k_attn (1280 blocks): logits + softmax + pool, wemb in registers (verified)
// ===========================================================================
__global__ __launch_bounds__(TPB)
void k_attn(Args A)
{
    __shared__ float red[16][4];
    __shared__ float att[16];
    const int t = blockIdx.x;
    const int b = t / NL;
    const int tid = threadIdx.x;
    const int lane = tid & 63, wid = tid >> 6;

    const float* w = A.wemb + (size_t)t * NM * ISZ;
    const int j0 = tid << 2;
    float4 u4 = *(const float4*)&A.uv[(size_t)b * ISZ + j0];

    float4 wv[NM];
    float part[NM];
    #pragma unroll
    for (int m = 0; m < NM; ++m) {
        wv[m] = *(const float4*)&w[m * ISZ + j0];
        part[m] = wv[m].x * u4.x + wv[m].y * u4.y + wv[m].z * u4.z + wv[m].w * u4.w;
    }
    #pragma unroll
    for (int m = 0; m < NM; ++m) {
        float v = part[m];
        #pragma unroll
        for (int off = 32; off > 0; off >>= 1) v += __shfl_down(v, off, 64);
        if (lane == 0) red[m][wid] = v;
    }
    __syncthreads();
    if (tid < NM) att[tid] = red[tid][0] + red[tid][1] + red[tid][2] + red[tid][3];
    __syncthreads();

    float mx = att[0];
    #pragma unroll
    for (int m = 1; m < NM; ++m) mx = fmaxf(mx, att[m]);
    float p[NM], sm = 0.0f;
    #pragma unroll
    for (int m = 0; m < NM; ++m) { p[m] = __expf(att[m] - mx); sm += p[m]; }
    float inv = 1.0f / sm;

    float4 acc = {0.0f, 0.0f, 0.0f, 0.0f};
    #pragma unroll
    for (int m = 0; m < NM; ++m) {
        float pm = p[m] * inv;
        acc.x += pm * wv[m].x; acc.y += pm * wv[m].y;
        acc.z += pm * wv[m].z; acc.w += pm * wv[m].w;
    }
    ushort4 o;
    o.x = f2bf(acc.x); o.y = f2bf(acc.y); o.z = f2bf(acc.z); o.w = f2bf(acc.w);
    *(ushort4*)&A.pooledb[(size_t)t * ISZ + j0] = o;
}

// ===========================================================================
// k_enc (160 blocks): BM=128, BN=64 MFMA GEMM (R2/R4/R5-verified body)
// out = pooled @ enc_w[:,:1024]^T + cenc[row/20]   (cenc includes enc_b)
// ===========================================================================
__global__ __launch_bounds__(TPB)
void k_enc(Args A)
{
    __shared__ __align__(16) unsigned char smem[24576];
    const int tid  = threadIdx.x;
    const int wid  = tid >> 6, lane = tid & 63;
    const int m0   = (blockIdx.x >> 4) * 128;
    const int n0   = (blockIdx.x & 15) * 64;
    const int ln   = lane & 15, kb = lane >> 4;
    const int wr   = wid >> 1, wc = wid & 1;
    const int srow = lane >> 3, sbyte = (lane & 7) << 4;
    const int swz  = sbyte ^ (srow << 4);

    f32x4 acc[4][2] = {};
    const char* Abase = (const char*)A.pooledb;
    const char* Bbase = (const char*)A.encb;

    for (int kt = 0; kt < 16; ++kt) {
        const int kbyte = kt * 128;
        #pragma unroll
        for (int i = 0; i < 4; ++i) {
            int r = wid * 8 + i * 32 + srow;
            gld_lds16(Abase + ((size_t)(m0 + r) * ISZ) * 2 + kbyte + swz,
                      (void*)(smem + wid * 1024 + i * 4096));
        }
        #pragma unroll
        for (int i = 0; i < 2; ++i) {
            int r = wid * 8 + i * 32 + srow;
            gld_lds16(Bbase + ((size_t)(n0 + r) * ISZ) * 2 + kbyte + swz,
                      (void*)(smem + 16384 + wid * 1024 + i * 4096));
        }
        __syncthreads();
        #pragma unroll
        for (int ks = 0; ks < 2; ++ks) {
            const int cb = (ks * 64 + kb * 16);
            bf16x8 a[4], b[2];
            #pragma unroll
            for (int m = 0; m < 4; ++m) {
                int ra = wr * 64 + m * 16 + ln;
                a[m] = *(const bf16x8*)(smem + ra * 128 + (cb ^ ((ra & 7) << 4)));
            }
            #pragma unroll
            for (int n = 0; n < 2; ++n) {
                int rb = wc * 32 + n * 16 + ln;
                b[n] = *(const bf16x8*)(smem + 16384 + rb * 128 + (cb ^ ((rb & 7) << 4)));
            }
            #pragma unroll
            for (int m = 0; m < 4; ++m)
                #pragma unroll
                for (int n = 0; n < 2; ++n)
                    acc[m][n] = __builtin_amdgcn_mfma_f32_16x16x32_bf16(a[m], b[n], acc[m][n], 0, 0, 0);
        }
        __syncthreads();
    }

    const int cl = lane & 15, rg = lane >> 4;
    #pragma unroll
    for (int m = 0; m < 4; ++m) {
        #pragma unroll
        for (int n = 0; n < 2; ++n) {
            int col = n0 + wc * 32 + n * 16 + cl;
            #pragma unroll
            for (int j = 0; j < 4; ++j) {
                int row = m0 + wr * 64 + m * 16 + rg * 4 + j;
                A.out[(size_t)row * ISZ + col] = acc[m][n][j] + A.cenc[(size_t)(row / NL) * ISZ + col];
            }
        }
    }
}

// ===========================================================================
// k_ln (1280): TF-style LayerNorm in-place on out (verified)
// ===========================================================================
__global__ __launch_bounds__(TPB)
void k_ln(Args A)
{
    __shared__ float rs[4], rs2[4];
    __shared__ float mu_s, rstd_s;
    const int t = blockIdx.x;
    const int tid = threadIdx.x;
    const int lane = tid & 63, wid = tid >> 6;
    const int c = tid << 2;

    float4 v = *(const float4*)&A.out[(size_t)t * ISZ + c];
    float s  = v.x + v.y + v.z + v.w;
    float s2 = v.x * v.x + v.y * v.y + v.z * v.z + v.w * v.w;
    #pragma unroll
    for (int off = 32; off > 0; off >>= 1) {
        s  += __shfl_down(s, off, 64);
        s2 += __shfl_down(s2, off, 64);
    }
    if (lane == 0) { rs[wid] = s; rs2[wid] = s2; }
    __syncthreads();
    if (tid == 0) {
        float S  = rs[0] + rs[1] + rs[2] + rs[3];
        float S2 = rs2[0] + rs2[1] + rs2[2] + rs2[3];
        float m  = S / ISZ;
        float var = S2 / ISZ - m * m;
        mu_s  = m;
        rstd_s = rsqrtf(var + 1e-12f);
    }
    __syncthreads();
    const float mu = mu_s, rstd = rstd_s;
    float4 g  = *(const float4*)&A.gamma[c];
    float4 be = *(const float4*)&A.beta[c];
    float4 o;
    o.x = g.x * (v.x - mu) * rstd + be.x;
    o.y = g.y * (v.y - mu) * rstd + be.y;
    o.z = g.z * (v.z - mu) * rstd + be.z;
    o.w = g.w * (v.w - mu) * rstd + be.w;
    *(float4*)&A.out[(size_t)t * ISZ + c] = o;
}

// ---------------------------------------------------------------------------
extern "C" void kernel_launch(void* const* d_in, const int* in_sizes, int n_in,
                              void* d_out, int out_size, void* d_ws, size_t ws_size,
                              hipStream_t stream)
{
    Args A;
    A.ctx   = (const float*)d_in[0];
    A.wemb  = (const float*)d_in[1];
    // d_in[2] l_hpu, d_in[3] l_hs: constant (16, 20) -> unused
    A.U_w   = (const float*)d_in[4];
    A.U_b   = (const float*)d_in[5];
    A.V_w   = (const float*)d_in[6];
    // d_in[7] V_b: constant logit offset per header, cancels in softmax
    A.enc_w = (const float*)d_in[8];
    A.enc_b = (const float*)d_in[9];
    A.gamma = (const float*)d_in[10];
    A.beta  = (const float*)d_in[11];
    A.out   = (float*)d_out;

    float* ws = (float*)d_ws;
    A.uv    = ws;                                    // 64*1024 f32  (zeroed in k_prep)
    A.Upart = ws + NB * ISZ;                         // 8*64*1024 f32
    A.Cpart = A.Upart + 8 * NB * ISZ;                // 8*64*1024 f32
    A.cenc  = A.Cpart + 8 * NB * ISZ;                // 64*1024 f32
    unsigned short* p = (unsigned short*)(A.cenc + NB * ISZ);
    A.Vth     = p;  p += ISZ * ISZ;                  // V^T hi
    A.Vtl     = p;  p += ISZ * ISZ;                  // V^T lo
    A.encb    = p;  p += ISZ * ISZ;                  // enc_w[:, :1024] bf16
    A.pooledb = p;                                   // 1280*1024 bf16

    k_prep<<<656, TPB, 0, stream>>>(A);
    k_mid <<<144, TPB, 0, stream>>>(A);
    k_attn<<<NT,  TPB, 0, stream>>>(A);
    k_enc <<<160, TPB, 0, stream>>>(A);
    k_ln  <<<NT,  TPB, 0, stream>>>(A);
}